// Round 1
// baseline (1186.560 us; speedup 1.0000x reference)
//
#include <hip/hip_runtime.h>
#include <hip/hip_bf16.h>
#include <stdint.h>

// Problem constants
#define T_TOK 8192      // B*S tokens
#define DMODEL 1024
#define FFDIM 4096
#define NEXP 8
#define TOPK 2
#define MTILES 72               // 256-row tiles: 16384 + 8*255 <= 72*256
#define ROWS_PAD (MTILES * 256) // 18432

typedef __bf16 bf16x8 __attribute__((ext_vector_type(8)));
typedef float f32x4 __attribute__((ext_vector_type(4)));

__device__ __forceinline__ unsigned short f2bf(float f) {
    union { float f; unsigned u; } v; v.f = f;
    unsigned u = v.u;
    u += 0x7fffu + ((u >> 16) & 1u);   // round-to-nearest-even
    return (unsigned short)(u >> 16);
}

// ---------------- init: zero out region, row_token=-1, zero_row, counters ----
__global__ void init_kernel(float* __restrict__ out0, int* __restrict__ row_token,
                            unsigned short* __restrict__ zero_row, int* __restrict__ cnt_fill) {
    size_t i = (size_t)blockIdx.x * blockDim.x + threadIdx.x;
    if (i < (size_t)T_TOK * DMODEL) out0[i] = 0.f;
    if (i < ROWS_PAD) row_token[i] = -1;
    if (i < DMODEL) zero_row[i] = 0;
    if (i < 16) cnt_fill[i] = 0;
}

// ---------------- fp32 -> bf16 conversion (vectorized) -----------------------
__global__ void cvt_kernel(const float* __restrict__ src, unsigned short* __restrict__ dst, int n4) {
    int i = blockIdx.x * blockDim.x + threadIdx.x;
    if (i < n4) {
        float4 v = ((const float4*)src)[i];
        ushort4 o;
        o.x = f2bf(v.x); o.y = f2bf(v.y); o.z = f2bf(v.z); o.w = f2bf(v.w);
        ((ushort4*)dst)[i] = o;
    }
}

// ---------------- gating: one wave per token, fp64 accumulation --------------
__global__ __launch_bounds__(256)
void gate_kernel(const float* __restrict__ x, const float* __restrict__ wg,
                 const float* __restrict__ bg,
                 float* __restrict__ out_idx, float* __restrict__ out_val,
                 int* __restrict__ tok_e, float* __restrict__ tok_g, int* __restrict__ cnt) {
    int t = blockIdx.x * 4 + (threadIdx.x >> 6);
    int lane = threadIdx.x & 63;
    const float4* xr = (const float4*)(x + (size_t)t * DMODEL);
    double acc[NEXP];
#pragma unroll
    for (int e = 0; e < NEXP; ++e) acc[e] = 0.0;
#pragma unroll
    for (int it = 0; it < 4; ++it) {
        float4 xv = xr[lane + it * 64];
#pragma unroll
        for (int e = 0; e < NEXP; ++e) {
            float4 wv = ((const float4*)(wg + e * DMODEL))[lane + it * 64];
            acc[e] += (double)xv.x * wv.x + (double)xv.y * wv.y +
                      (double)xv.z * wv.z + (double)xv.w * wv.w;
        }
    }
#pragma unroll
    for (int off = 32; off; off >>= 1)
#pragma unroll
        for (int e = 0; e < NEXP; ++e) acc[e] += __shfl_down(acc[e], off, 64);
    if (lane == 0) {
        double lg[NEXP], mx = -1e300;
#pragma unroll
        for (int e = 0; e < NEXP; ++e) { lg[e] = acc[e] + (double)bg[e]; mx = lg[e] > mx ? lg[e] : mx; }
        double p[NEXP], s = 0.0;
#pragma unroll
        for (int e = 0; e < NEXP; ++e) { p[e] = exp(lg[e] - mx); s += p[e]; }
#pragma unroll
        for (int e = 0; e < NEXP; ++e) p[e] /= s;
        int i0 = 0;
#pragma unroll
        for (int e = 1; e < NEXP; ++e) if (p[e] > p[i0]) i0 = e;
        int i1 = (i0 == 0) ? 1 : 0;
#pragma unroll
        for (int e = 0; e < NEXP; ++e) if (e != i0 && p[e] > p[i1]) i1 = e;
        out_idx[t * 2 + 0] = (float)i0;
        out_idx[t * 2 + 1] = (float)i1;
        out_val[t * 2 + 0] = (float)p[i0];
        out_val[t * 2 + 1] = (float)p[i1];
        tok_e[t * 2 + 0] = i0; tok_e[t * 2 + 1] = i1;
        tok_g[t * 2 + 0] = (float)p[i0]; tok_g[t * 2 + 1] = (float)p[i1];
        atomicAdd(&cnt[i0], 1);
        atomicAdd(&cnt[i1], 1);
    }
}

// ---------------- 256-padded segment offsets ---------------------------------
__global__ void offsets_kernel(const int* __restrict__ cnt, int* __restrict__ off_pad) {
    if (threadIdx.x == 0 && blockIdx.x == 0) {
        int o = 0;
        off_pad[0] = 0;
#pragma unroll
        for (int e = 0; e < NEXP; ++e) {
            o += ((cnt[e] + 255) >> 8) << 8;
            off_pad[e + 1] = o;
        }
    }
}

// ---------------- scatter tokens into padded row space -----------------------
__global__ void scatter_kernel(const int* __restrict__ tok_e, const float* __restrict__ tok_g,
                               const int* __restrict__ off_pad, int* __restrict__ fill,
                               int* __restrict__ row_token, float* __restrict__ row_gate) {
    int i = blockIdx.x * blockDim.x + threadIdx.x;
    if (i < T_TOK * TOPK) {
        int e = tok_e[i];
        int pos = off_pad[e] + atomicAdd(&fill[e], 1);
        row_token[pos] = i >> 1;
        row_gate[pos] = tok_g[i];
    }
}

// ---------------- grouped GEMM: 256x256 tile, BK=32, 4-deep LDS ring ---------
// C = A * W^T. 512 threads = 8 waves (2M x 4N), per-wave output 128x64.
// LDS: 4 ring buffers x (256 A-rows + 256 B-rows) x 32 cols bf16 = 128 KiB.
// Pipeline (T3+T4): stage tile t+3 AFTER iter t's barrier; certify tile t with
// a COUNTED s_waitcnt vmcnt(8) (4 loads/thread/tile, 2 tiles stay in flight) +
// one raw s_barrier per K-tile. No vmcnt(0) drain in the main loop -> loads
// have ~3 K-tile times (>3000 cyc) to land vs HBM ~900 cyc.
// Race safety: buf[(t+3)&3] == buf[(t-1)&3]; its readers (tile t-1, iter t-1)
// all passed iter t's barrier before the stage issues. Tile t's data was
// certified by iter t-1's vmcnt+barrier (collective across all waves).
// Swizzle: physical chunk = logical chunk ^ ((row>>1)&3) -- identical algebra
// to the verified-0-conflict 128-tile variant (all row deltas are mult. of 16).
// T5: setprio(1) around the 32-MFMA cluster.
// MODE 0: A = gathered x_bf16 rows, store h = leakyrelu(C + b1) as bf16
// MODE 1: A = h rows, atomicAdd gate*(C + [z==0]*b2) into out; K split ZS ways
template <int MODE, int KD, int ND, int ZS>
__global__ __launch_bounds__(512, 2)
void moe_gemm(const unsigned short* __restrict__ A, const unsigned short* __restrict__ W,
              const float* __restrict__ bias, const int* __restrict__ row_token,
              const float* __restrict__ row_gate, const int* __restrict__ off_pad,
              const unsigned short* __restrict__ zero_row,
              unsigned short* __restrict__ Hout, float* __restrict__ Out) {
    __shared__ __attribute__((aligned(16))) unsigned short As[4 * 256 * 32];
    __shared__ __attribute__((aligned(16))) unsigned short Bs[4 * 256 * 32];
    const int m0 = blockIdx.x * 256;
    const int n0 = blockIdx.y * 256;
    const int kbase = (ZS > 1) ? (int)blockIdx.z * (KD / ZS) : 0;
    constexpr int NT = KD / ZS / 32;   // K-tiles this block processes

    // expert for this row tile (off_pad monotone, 256-aligned; last true wins)
    int e = 0;
#pragma unroll
    for (int q = 0; q < NEXP - 1; ++q)
        if (off_pad[q + 1] <= m0) e = q + 1;

    const int tid = threadIdx.x;
    const int wave = tid >> 6;
    const int lane = tid & 63;
    const int wm = wave >> 2, wn = wave & 3;       // 2 x 4 wave grid
    const int lane15 = lane & 15;
    const int quad = lane >> 4;

    // staging geometry: 256 rows x 4 chunks (16B) per matrix = 1024 chunks,
    // 2 rounds of 512 threads. row = r*128 + (tid>>2), logical chunk = tid&3.
    // swizzled source chunk: (tid&3) ^ ((row>>1)&3); r*128 leaves (row>>1)&3
    // unchanged so it's r-invariant.
    const int scol = (tid & 3) ^ ((tid >> 3) & 3);

    const unsigned short* aptr[2];
    const unsigned short* bptr[2];
#pragma unroll
    for (int r = 0; r < 2; ++r) {
        int row = r * 128 + (tid >> 2);
        const unsigned short* ab;
        if (MODE == 0) {
            int tok = row_token[m0 + row];
            ab = (tok < 0) ? zero_row : (A + (size_t)tok * KD);
        } else {
            ab = A + (size_t)(m0 + row) * KD;
        }
        aptr[r] = ab + kbase + scol * 8;
        bptr[r] = W + ((size_t)e * ND + (size_t)(n0 + row)) * (size_t)KD + kbase + scol * 8;
    }

    f32x4 acc[8][4];
#pragma unroll
    for (int i = 0; i < 8; ++i)
#pragma unroll
        for (int j = 0; j < 4; ++j) acc[i][j] = (f32x4)0.f;

    const int rowA = wm * 128 + lane15;    // + i*16 per fragment
    const int rowB = wn * 64 + lane15;     // + j*16 per fragment
    const int pcs = ((quad ^ ((lane15 >> 1) & 3)) * 8);  // physical chunk (shorts)

    // stage one K-tile (4 global_load_lds per thread); dest is wave-uniform
    // base + lane*16B (hardware adds the lane term).
    auto stage = [&](int tt) {
        const int bo = (tt & 3) * 8192;
        const int koff = tt * 32;
#pragma unroll
        for (int r = 0; r < 2; ++r) {
            __builtin_amdgcn_global_load_lds(
                (const __attribute__((address_space(1))) void*)(aptr[r] + koff),
                (__attribute__((address_space(3))) void*)(As + bo + (r * 512 + wave * 64) * 8), 16, 0, 0);
            __builtin_amdgcn_global_load_lds(
                (const __attribute__((address_space(1))) void*)(bptr[r] + koff),
                (__attribute__((address_space(3))) void*)(Bs + bo + (r * 512 + wave * 64) * 8), 16, 0, 0);
        }
    };

    // prologue: fill 3 ring slots (12 loads in flight)
    stage(0); stage(1); stage(2);

    for (int t = 0; t < NT; ++t) {
        // certify tile t: wait down to the 2 youngest prefetched tiles
        if (t < NT - 2)       asm volatile("s_waitcnt vmcnt(8)" ::: "memory");
        else if (t == NT - 2) asm volatile("s_waitcnt vmcnt(4)" ::: "memory");
        else                  asm volatile("s_waitcnt vmcnt(0)" ::: "memory");
        __builtin_amdgcn_s_barrier();
        asm volatile("" ::: "memory");
        if (t + 3 < NT) stage(t + 3);   // overwrites buf[(t-1)&3]: readers done

        const int bo = (t & 3) * 8192;
        bf16x8 bfv[4], af[8];
#pragma unroll
        for (int j = 0; j < 4; ++j)
            bfv[j] = *(const bf16x8*)(Bs + bo + (rowB + j * 16) * 32 + pcs);
#pragma unroll
        for (int i = 0; i < 8; ++i)
            af[i] = *(const bf16x8*)(As + bo + (rowA + i * 16) * 32 + pcs);
        __builtin_amdgcn_s_setprio(1);
#pragma unroll
        for (int i = 0; i < 8; ++i)
#pragma unroll
            for (int j = 0; j < 4; ++j)
                acc[i][j] = __builtin_amdgcn_mfma_f32_16x16x32_bf16(af[i], bfv[j], acc[i][j], 0, 0, 0);
        __builtin_amdgcn_s_setprio(0);
    }

    // epilogue
    const bool add_bias = (MODE == 0) || (kbase == 0);
    float bv[4];
#pragma unroll
    for (int j = 0; j < 4; ++j)
        bv[j] = bias[e * ND + n0 + wn * 64 + j * 16 + lane15];
#pragma unroll
    for (int i = 0; i < 8; ++i) {
#pragma unroll
        for (int r4 = 0; r4 < 4; ++r4) {
            int m = m0 + wm * 128 + i * 16 + quad * 4 + r4;
            int tok = 0; float g = 0.f;
            if (MODE == 1) { tok = row_token[m]; g = row_gate[m]; }
#pragma unroll
            for (int j = 0; j < 4; ++j) {
                int n = n0 + wn * 64 + j * 16 + lane15;
                float v = acc[i][j][r4] + (add_bias ? bv[j] : 0.f);
                if (MODE == 0) {
                    v = v > 0.f ? v : 0.1f * v;
                    Hout[(size_t)m * ND + n] = f2bf(v);
                } else {
                    if (tok >= 0) atomicAdd(Out + (size_t)tok * ND + n, g * v);
                }
            }
        }
    }
}

extern "C" void kernel_launch(void* const* d_in, const int* in_sizes, int n_in,
                              void* d_out, int out_size, void* d_ws, size_t ws_size,
                              hipStream_t stream) {
    const float* x  = (const float*)d_in[0];
    const float* wg = (const float*)d_in[1];
    const float* bg = (const float*)d_in[2];
    const float* w1 = (const float*)d_in[3];
    const float* b1 = (const float*)d_in[4];
    const float* w2 = (const float*)d_in[5];
    const float* b2 = (const float*)d_in[6];
    float* out0 = (float*)d_out;
    float* out_idx = out0 + (size_t)T_TOK * DMODEL;
    float* out_val = out_idx + T_TOK * TOPK;

    char* p = (char*)d_ws;
    auto alloc = [&](size_t bytes) {
        char* q = p;
        p += (bytes + 255) & ~(size_t)255;
        return q;
    };
    unsigned short* xb  = (unsigned short*)alloc((size_t)T_TOK * DMODEL * 2);
    unsigned short* w1b = (unsigned short*)alloc((size_t)NEXP * FFDIM * DMODEL * 2);
    unsigned short* w2b = (unsigned short*)alloc((size_t)NEXP * DMODEL * FFDIM * 2);
    unsigned short* hb  = (unsigned short*)alloc((size_t)ROWS_PAD * FFDIM * 2);
    unsigned short* zrow = (unsigned short*)alloc(DMODEL * 2);
    int* cnt = (int*)alloc(64);   // cnt[8] + fill[8]
    int* fill = cnt + 8;
    int* off_pad = (int*)alloc(64);
    int* tok_e = (int*)alloc((size_t)T_TOK * TOPK * 4);
    float* tok_g = (float*)alloc((size_t)T_TOK * TOPK * 4);
    int* row_token = (int*)alloc((size_t)ROWS_PAD * 4);
    float* row_gate = (float*)alloc((size_t)ROWS_PAD * 4);
    if ((size_t)(p - (char*)d_ws) > ws_size) return;  // ws too small: fail visibly, no OOB

    init_kernel<<<(T_TOK * DMODEL + 255) / 256, 256, 0, stream>>>(out0, row_token, zrow, cnt);
    cvt_kernel<<<(T_TOK * DMODEL / 4 + 255) / 256, 256, 0, stream>>>(x, xb, T_TOK * DMODEL / 4);
    cvt_kernel<<<(NEXP * FFDIM * DMODEL / 4 + 255) / 256, 256, 0, stream>>>(w1, w1b, NEXP * FFDIM * DMODEL / 4);
    cvt_kernel<<<(NEXP * DMODEL * FFDIM / 4 + 255) / 256, 256, 0, stream>>>(w2, w2b, NEXP * DMODEL * FFDIM / 4);
    gate_kernel<<<T_TOK / 4, 256, 0, stream>>>(x, wg, bg, out_idx, out_val, tok_e, tok_g, cnt);
    offsets_kernel<<<1, 64, 0, stream>>>(cnt, off_pad);
    scatter_kernel<<<(T_TOK * TOPK + 255) / 256, 256, 0, stream>>>(tok_e, tok_g, off_pad, fill, row_token, row_gate);
    moe_gemm<0, DMODEL, FFDIM, 1><<<dim3(MTILES, FFDIM / 256, 1), 512, 0, stream>>>(
        xb, w1b, b1, row_token, row_gate, off_pad, zrow, hb, nullptr);
    moe_gemm<1, FFDIM, DMODEL, 2><<<dim3(MTILES, DMODEL / 256, 2), 512, 0, stream>>>(
        hb, w2b, b2, row_token, row_gate, off_pad, zrow, nullptr, out0);
}

// Round 2
// 1099.792 us; speedup vs baseline: 1.0789x; 1.0789x over previous
//
#include <hip/hip_runtime.h>
#include <hip/hip_bf16.h>
#include <stdint.h>

// Problem constants
#define T_TOK 8192      // B*S tokens
#define DMODEL 1024
#define FFDIM 4096
#define NEXP 8
#define TOPK 2
#define MTILES 72               // 256-row tiles: 16384 + 8*255 <= 72*256
#define ROWS_PAD (MTILES * 256) // 18432

typedef __bf16 bf16x8 __attribute__((ext_vector_type(8)));
typedef float f32x4 __attribute__((ext_vector_type(4)));

__device__ __forceinline__ unsigned short f2bf(float f) {
    union { float f; unsigned u; } v; v.f = f;
    unsigned u = v.u;
    u += 0x7fffu + ((u >> 16) & 1u);   // round-to-nearest-even
    return (unsigned short)(u >> 16);
}

// ---------------- init: zero out region, row_token=-1, zero_row, counters ----
__global__ void init_kernel(float* __restrict__ out0, int* __restrict__ row_token,
                            unsigned short* __restrict__ zero_row, int* __restrict__ cnt_fill) {
    size_t i = (size_t)blockIdx.x * blockDim.x + threadIdx.x;
    if (i < (size_t)T_TOK * DMODEL) out0[i] = 0.f;
    if (i < ROWS_PAD) row_token[i] = -1;
    if (i < DMODEL) zero_row[i] = 0;
    if (i < 16) cnt_fill[i] = 0;
}

// ---------------- fp32 -> bf16 conversion (vectorized) -----------------------
__global__ void cvt_kernel(const float* __restrict__ src, unsigned short* __restrict__ dst, int n4) {
    int i = blockIdx.x * blockDim.x + threadIdx.x;
    if (i < n4) {
        float4 v = ((const float4*)src)[i];
        ushort4 o;
        o.x = f2bf(v.x); o.y = f2bf(v.y); o.z = f2bf(v.z); o.w = f2bf(v.w);
        ((ushort4*)dst)[i] = o;
    }
}

// ---------------- gating: one wave per token, fp64 accumulation --------------
__global__ __launch_bounds__(256)
void gate_kernel(const float* __restrict__ x, const float* __restrict__ wg,
                 const float* __restrict__ bg,
                 float* __restrict__ out_idx, float* __restrict__ out_val,
                 int* __restrict__ tok_e, float* __restrict__ tok_g, int* __restrict__ cnt) {
    int t = blockIdx.x * 4 + (threadIdx.x >> 6);
    int lane = threadIdx.x & 63;
    const float4* xr = (const float4*)(x + (size_t)t * DMODEL);
    double acc[NEXP];
#pragma unroll
    for (int e = 0; e < NEXP; ++e) acc[e] = 0.0;
#pragma unroll
    for (int it = 0; it < 4; ++it) {
        float4 xv = xr[lane + it * 64];
#pragma unroll
        for (int e = 0; e < NEXP; ++e) {
            float4 wv = ((const float4*)(wg + e * DMODEL))[lane + it * 64];
            acc[e] += (double)xv.x * wv.x + (double)xv.y * wv.y +
                      (double)xv.z * wv.z + (double)xv.w * wv.w;
        }
    }
#pragma unroll
    for (int off = 32; off; off >>= 1)
#pragma unroll
        for (int e = 0; e < NEXP; ++e) acc[e] += __shfl_down(acc[e], off, 64);
    if (lane == 0) {
        double lg[NEXP], mx = -1e300;
#pragma unroll
        for (int e = 0; e < NEXP; ++e) { lg[e] = acc[e] + (double)bg[e]; mx = lg[e] > mx ? lg[e] : mx; }
        double p[NEXP], s = 0.0;
#pragma unroll
        for (int e = 0; e < NEXP; ++e) { p[e] = exp(lg[e] - mx); s += p[e]; }
#pragma unroll
        for (int e = 0; e < NEXP; ++e) p[e] /= s;
        int i0 = 0;
#pragma unroll
        for (int e = 1; e < NEXP; ++e) if (p[e] > p[i0]) i0 = e;
        int i1 = (i0 == 0) ? 1 : 0;
#pragma unroll
        for (int e = 0; e < NEXP; ++e) if (e != i0 && p[e] > p[i1]) i1 = e;
        out_idx[t * 2 + 0] = (float)i0;
        out_idx[t * 2 + 1] = (float)i1;
        out_val[t * 2 + 0] = (float)p[i0];
        out_val[t * 2 + 1] = (float)p[i1];
        tok_e[t * 2 + 0] = i0; tok_e[t * 2 + 1] = i1;
        tok_g[t * 2 + 0] = (float)p[i0]; tok_g[t * 2 + 1] = (float)p[i1];
        atomicAdd(&cnt[i0], 1);
        atomicAdd(&cnt[i1], 1);
    }
}

// ---------------- 256-padded segment offsets ---------------------------------
__global__ void offsets_kernel(const int* __restrict__ cnt, int* __restrict__ off_pad) {
    if (threadIdx.x == 0 && blockIdx.x == 0) {
        int o = 0;
        off_pad[0] = 0;
#pragma unroll
        for (int e = 0; e < NEXP; ++e) {
            o += ((cnt[e] + 255) >> 8) << 8;
            off_pad[e + 1] = o;
        }
    }
}

// ---------------- scatter tokens into padded row space -----------------------
__global__ void scatter_kernel(const int* __restrict__ tok_e, const float* __restrict__ tok_g,
                               const int* __restrict__ off_pad, int* __restrict__ fill,
                               int* __restrict__ row_token, float* __restrict__ row_gate) {
    int i = blockIdx.x * blockDim.x + threadIdx.x;
    if (i < T_TOK * TOPK) {
        int e = tok_e[i];
        int pos = off_pad[e] + atomicAdd(&fill[e], 1);
        row_token[pos] = i >> 1;
        row_gate[pos] = tok_g[i];
    }
}

// ---------------- grouped GEMM: 256x256 tile, BK=32, ring-4 LDS, fine phases -
// C = A * W^T. 512 threads = 8 waves (2M x 4N), per-wave output 128x64.
// LDS: ring of 4 x (256 A-rows + 256 B-rows) x 32 cols bf16 = 128 KiB
// (1 block/CU; pipeline depth substitutes for TLP, per the 8-phase template).
// Each K-tile = 2 fine phases (m201 schedule, T3+T4+T5):
//   P0: ds_read af[0..3]+bfv[0..3]; stage A(t+3); barrier; lgkmcnt(0)+
//       sched_barrier; setprio(1); 16 MFMA; setprio(0); barrier
//   P1: ds_read af[4..7] (bfv reused in regs); stage B(t+3); barrier;
//       lgkmcnt(0)+sched_barrier; setprio(1); 16 MFMA; setprio(0)
//   tile end: COUNTED s_waitcnt vmcnt(8) certifies tile t+1 (12 loads in
//   flight, wait oldest 4; never 0 mid-loop) + barrier.
// Race safety: stage(t+3) overwrites buf[(t-1)&3]; every wave's reads of
// tile t-1 returned before its lgkmcnt(0) in tile t-1, which precedes the
// tile-(t-1)-end barrier, which precedes any stage(t+3) issue.
// Swizzle: physical chunk = logical chunk ^ ((row>>1)&3) (verified 0-conflict).
// MODE 0: A = gathered x_bf16 rows, store h = leakyrelu(C + b1) as bf16
// MODE 1: A = h rows, atomicAdd gate*(C + [z==0]*b2) into out; K split ZS ways
template <int MODE, int KD, int ND, int ZS>
__global__ __launch_bounds__(512, 2)
void moe_gemm(const unsigned short* __restrict__ A, const unsigned short* __restrict__ W,
              const float* __restrict__ bias, const int* __restrict__ row_token,
              const float* __restrict__ row_gate, const int* __restrict__ off_pad,
              const unsigned short* __restrict__ zero_row,
              unsigned short* __restrict__ Hout, float* __restrict__ Out) {
    __shared__ __attribute__((aligned(16))) unsigned short As[4 * 256 * 32];
    __shared__ __attribute__((aligned(16))) unsigned short Bs[4 * 256 * 32];
    const int m0 = blockIdx.x * 256;
    const int n0 = blockIdx.y * 256;
    const int kbase = (ZS > 1) ? (int)blockIdx.z * (KD / ZS) : 0;
    constexpr int NT = KD / ZS / 32;   // K-tiles this block processes

    // expert for this row tile (off_pad monotone, 256-aligned; last true wins)
    int e = 0;
#pragma unroll
    for (int q = 0; q < NEXP - 1; ++q)
        if (off_pad[q + 1] <= m0) e = q + 1;

    const int tid = threadIdx.x;
    const int wave = tid >> 6;
    const int lane = tid & 63;
    const int wm = wave >> 2, wn = wave & 3;       // 2 x 4 wave grid
    const int lane15 = lane & 15;
    const int quad = lane >> 4;

    // staging geometry: 256 rows x 4 chunks (16B) per matrix = 1024 chunks,
    // 2 rounds of 512 threads. row = r*128 + (tid>>2), logical chunk = tid&3.
    // swizzled source chunk: (tid&3) ^ ((row>>1)&3), r-invariant.
    const int scol = (tid & 3) ^ ((tid >> 3) & 3);

    const unsigned short* aptr[2];
    const unsigned short* bptr[2];
#pragma unroll
    for (int r = 0; r < 2; ++r) {
        int row = r * 128 + (tid >> 2);
        const unsigned short* ab;
        if (MODE == 0) {
            int tok = row_token[m0 + row];
            ab = (tok < 0) ? zero_row : (A + (size_t)tok * KD);
        } else {
            ab = A + (size_t)(m0 + row) * KD;
        }
        aptr[r] = ab + kbase + scol * 8;
        bptr[r] = W + ((size_t)e * ND + (size_t)(n0 + row)) * (size_t)KD + kbase + scol * 8;
    }

    f32x4 acc[8][4];
#pragma unroll
    for (int i = 0; i < 8; ++i)
#pragma unroll
        for (int j = 0; j < 4; ++j) acc[i][j] = (f32x4)0.f;

    const int rowA = wm * 128 + lane15;    // + i*16 per fragment
    const int rowB = wn * 64 + lane15;     // + j*16 per fragment
    const int pcs = ((quad ^ ((lane15 >> 1) & 3)) * 8);  // physical chunk (shorts)

    // stage half: 2 global_load_lds per thread per matrix per tile
    auto stageA = [&](int tt) {
        const int bo = (tt & 3) * 8192;
        const int koff = tt * 32;
#pragma unroll
        for (int r = 0; r < 2; ++r)
            __builtin_amdgcn_global_load_lds(
                (const __attribute__((address_space(1))) void*)(aptr[r] + koff),
                (__attribute__((address_space(3))) void*)(As + bo + (r * 512 + wave * 64) * 8), 16, 0, 0);
    };
    auto stageB = [&](int tt) {
        const int bo = (tt & 3) * 8192;
        const int koff = tt * 32;
#pragma unroll
        for (int r = 0; r < 2; ++r)
            __builtin_amdgcn_global_load_lds(
                (const __attribute__((address_space(1))) void*)(bptr[r] + koff),
                (__attribute__((address_space(3))) void*)(Bs + bo + (r * 512 + wave * 64) * 8), 16, 0, 0);
    };

    // prologue: fill 3 ring slots (12 loads in flight), certify tile 0
    stageA(0); stageB(0); stageA(1); stageB(1); stageA(2); stageB(2);
    asm volatile("s_waitcnt vmcnt(8)" ::: "memory");
    __builtin_amdgcn_s_barrier();

    for (int t = 0; t < NT; ++t) {
        const int bo = (t & 3) * 8192;
        // -------- phase 0: C-rows 0..63 of this wave --------
        bf16x8 af0[4], bfv[4];
#pragma unroll
        for (int i = 0; i < 4; ++i)
            af0[i] = *(const bf16x8*)(As + bo + (rowA + i * 16) * 32 + pcs);
#pragma unroll
        for (int j = 0; j < 4; ++j)
            bfv[j] = *(const bf16x8*)(Bs + bo + (rowB + j * 16) * 32 + pcs);
        if (t + 3 < NT) stageA(t + 3);
        __builtin_amdgcn_s_barrier();
        asm volatile("s_waitcnt lgkmcnt(0)" ::: "memory");
        __builtin_amdgcn_sched_barrier(0);
        __builtin_amdgcn_s_setprio(1);
#pragma unroll
        for (int i = 0; i < 4; ++i)
#pragma unroll
            for (int j = 0; j < 4; ++j)
                acc[i][j] = __builtin_amdgcn_mfma_f32_16x16x32_bf16(af0[i], bfv[j], acc[i][j], 0, 0, 0);
        __builtin_amdgcn_s_setprio(0);
        __builtin_amdgcn_s_barrier();
        // -------- phase 1: C-rows 64..127 (bfv reused from registers) --------
        bf16x8 af1[4];
#pragma unroll
        for (int i = 0; i < 4; ++i)
            af1[i] = *(const bf16x8*)(As + bo + (rowA + 64 + i * 16) * 32 + pcs);
        if (t + 3 < NT) stageB(t + 3);
        __builtin_amdgcn_s_barrier();
        asm volatile("s_waitcnt lgkmcnt(0)" ::: "memory");
        __builtin_amdgcn_sched_barrier(0);
        __builtin_amdgcn_s_setprio(1);
#pragma unroll
        for (int i = 0; i < 4; ++i)
#pragma unroll
            for (int j = 0; j < 4; ++j)
                acc[4 + i][j] = __builtin_amdgcn_mfma_f32_16x16x32_bf16(af1[i], bfv[j], acc[4 + i][j], 0, 0, 0);
        __builtin_amdgcn_s_setprio(0);
        // -------- tile end: certify tile t+1 with counted vmcnt --------
        if (t < NT - 1) {
            if (t < NT - 3)       asm volatile("s_waitcnt vmcnt(8)" ::: "memory");
            else if (t == NT - 3) asm volatile("s_waitcnt vmcnt(4)" ::: "memory");
            else                  asm volatile("s_waitcnt vmcnt(0)" ::: "memory");
            __builtin_amdgcn_s_barrier();
        }
    }

    // epilogue
    const bool add_bias = (MODE == 0) || (kbase == 0);
    float bv[4];
#pragma unroll
    for (int j = 0; j < 4; ++j)
        bv[j] = bias[e * ND + n0 + wn * 64 + j * 16 + lane15];
#pragma unroll
    for (int i = 0; i < 8; ++i) {
#pragma unroll
        for (int r4 = 0; r4 < 4; ++r4) {
            int m = m0 + wm * 128 + i * 16 + quad * 4 + r4;
            int tok = 0; float g = 0.f;
            if (MODE == 1) { tok = row_token[m]; g = row_gate[m]; }
#pragma unroll
            for (int j = 0; j < 4; ++j) {
                int n = n0 + wn * 64 + j * 16 + lane15;
                float v = acc[i][j][r4] + (add_bias ? bv[j] : 0.f);
                if (MODE == 0) {
                    v = v > 0.f ? v : 0.1f * v;
                    Hout[(size_t)m * ND + n] = f2bf(v);
                } else {
                    if (tok >= 0) atomicAdd(Out + (size_t)tok * ND + n, g * v);
                }
            }
        }
    }
}

extern "C" void kernel_launch(void* const* d_in, const int* in_sizes, int n_in,
                              void* d_out, int out_size, void* d_ws, size_t ws_size,
                              hipStream_t stream) {
    const float* x  = (const float*)d_in[0];
    const float* wg = (const float*)d_in[1];
    const float* bg = (const float*)d_in[2];
    const float* w1 = (const float*)d_in[3];
    const float* b1 = (const float*)d_in[4];
    const float* w2 = (const float*)d_in[5];
    const float* b2 = (const float*)d_in[6];
    float* out0 = (float*)d_out;
    float* out_idx = out0 + (size_t)T_TOK * DMODEL;
    float* out_val = out_idx + T_TOK * TOPK;

    char* p = (char*)d_ws;
    auto alloc = [&](size_t bytes) {
        char* q = p;
        p += (bytes + 255) & ~(size_t)255;
        return q;
    };
    unsigned short* xb  = (unsigned short*)alloc((size_t)T_TOK * DMODEL * 2);
    unsigned short* w1b = (unsigned short*)alloc((size_t)NEXP * FFDIM * DMODEL * 2);
    unsigned short* w2b = (unsigned short*)alloc((size_t)NEXP * DMODEL * FFDIM * 2);
    unsigned short* hb  = (unsigned short*)alloc((size_t)ROWS_PAD * FFDIM * 2);
    unsigned short* zrow = (unsigned short*)alloc(DMODEL * 2);
    int* cnt = (int*)alloc(64);   // cnt[8] + fill[8]
    int* fill = cnt + 8;
    int* off_pad = (int*)alloc(64);
    int* tok_e = (int*)alloc((size_t)T_TOK * TOPK * 4);
    float* tok_g = (float*)alloc((size_t)T_TOK * TOPK * 4);
    int* row_token = (int*)alloc((size_t)ROWS_PAD * 4);
    float* row_gate = (float*)alloc((size_t)ROWS_PAD * 4);
    if ((size_t)(p - (char*)d_ws) > ws_size) return;  // ws too small: fail visibly, no OOB

    init_kernel<<<(T_TOK * DMODEL + 255) / 256, 256, 0, stream>>>(out0, row_token, zrow, cnt);
    cvt_kernel<<<(T_TOK * DMODEL / 4 + 255) / 256, 256, 0, stream>>>(x, xb, T_TOK * DMODEL / 4);
    cvt_kernel<<<(NEXP * FFDIM * DMODEL / 4 + 255) / 256, 256, 0, stream>>>(w1, w1b, NEXP * FFDIM * DMODEL / 4);
    cvt_kernel<<<(NEXP * DMODEL * FFDIM / 4 + 255) / 256, 256, 0, stream>>>(w2, w2b, NEXP * DMODEL * FFDIM / 4);
    gate_kernel<<<T_TOK / 4, 256, 0, stream>>>(x, wg, bg, out_idx, out_val, tok_e, tok_g, cnt);
    offsets_kernel<<<1, 64, 0, stream>>>(cnt, off_pad);
    scatter_kernel<<<(T_TOK * TOPK + 255) / 256, 256, 0, stream>>>(tok_e, tok_g, off_pad, fill, row_token, row_gate);
    moe_gemm<0, DMODEL, FFDIM, 1><<<dim3(MTILES, FFDIM / 256, 1), 512, 0, stream>>>(
        xb, w1b, b1, row_token, row_gate, off_pad, zrow, hb, nullptr);
    moe_gemm<1, FFDIM, DMODEL, 2><<<dim3(MTILES, DMODEL / 256, 2), 512, 0, stream>>>(
        hb, w2b, b2, row_token, row_gate, off_pad, zrow, nullptr, out0);
}